// Round 11
// baseline (185.196 us; speedup 1.0000x reference)
//
#include <hip/hip_runtime.h>

// NT-Xent loss. Round 11: 128^2-tile 8-phase GEMM at 2 blocks/CU (TLP).
//   k_normalize : f32->bf16 Z, zero sumexp, dot(z_i,z_0) from raw X
//   k_gemm_lse  : 2080 triangular 128^2 tiles, 4 waves, BK=64, 64KB LDS,
//                 same 8-phase fenced schedule; fused exp row+col sums.
//   k_finalize  : ONE block: mean(10 + log(sumexp) - 10*dot) -> out

typedef unsigned short ushort_t;
typedef __attribute__((ext_vector_type(8))) short short8;
typedef __attribute__((ext_vector_type(4))) float f32x4;

#define N_ROWS 8192
#define N_DIM  1024

__device__ __forceinline__ float bf2f(ushort_t u) {
    return __uint_as_float(((unsigned int)u) << 16);
}
__device__ __forceinline__ ushort_t f2bf(float f) {
    unsigned int u = __float_as_uint(f);
    return (ushort_t)((u + 0x7FFFu + ((u >> 16) & 1u)) >> 16);  // RNE
}

// ---------------------------------------------------------------- kernel 1
__global__ __launch_bounds__(256) void k_normalize(const float* __restrict__ X,
                                                   ushort_t* __restrict__ Z,
                                                   float* __restrict__ sumexp,
                                                   float* __restrict__ dotz) {
    const int lane = threadIdx.x & 63;
    const int wid  = threadIdx.x >> 6;
    const int row  = blockIdx.x * 4 + wid;

    float4 v  = ((const float4*)(X + (size_t)row * N_DIM))[lane];
    float4 v0 = ((const float4*)X)[lane];

    float ss  = v.x * v.x + v.y * v.y + v.z * v.z + v.w * v.w;
    float s0  = v.x * v0.x + v.y * v0.y + v.z * v0.z + v.w * v0.w;
    float ss0 = v0.x * v0.x + v0.y * v0.y + v0.z * v0.z + v0.w * v0.w;
    #pragma unroll
    for (int off = 32; off; off >>= 1) {
        ss  += __shfl_xor(ss, off);
        s0  += __shfl_xor(s0, off);
        ss0 += __shfl_xor(ss0, off);
    }
    float inv  = 1.0f / fmaxf(sqrtf(ss), 1e-8f);
    float inv0 = 1.0f / fmaxf(sqrtf(ss0), 1e-8f);

    ushort4 o;
    o.x = f2bf(v.x * inv);
    o.y = f2bf(v.y * inv);
    o.z = f2bf(v.z * inv);
    o.w = f2bf(v.w * inv);
    ((ushort4*)(Z + (size_t)row * N_DIM))[lane] = o;

    if (lane == 0) {
        sumexp[row] = 0.0f;
        dotz[row]   = s0 * inv * inv0;
    }
}

// ---------------------------------------------------------------- kernel 2
// 128^2 tile, BK=64, 4 waves (2M x 2N), 8-phase schedule. LDS 64 KiB:
// A[dbuf][half] half = 64 rows x 64 cols bf16 = 8 KB (4096 ushorts).
// Swizzle identical to rounds 6-10: 16B unit cu = cl ^ (rl & 7).
#define LDSA(d, h) (((d)*2 + (h)) * 4096)
#define LDSB(d, h) (16384 + ((d)*2 + (h)) * 4096)

#define STAGE(baseoff, panel, h, tt) do {                                         \
    _Pragma("unroll")                                                             \
    for (int p_ = 0; p_ < 2; ++p_) {                                              \
        int rl_ = (p_*4 + w)*8 + srow;                                            \
        const ushort_t* src_ = Z + (size_t)((panel) + (h)*64 + rl_) * N_DIM       \
                                 + (tt)*64 + scol*8;                              \
        __builtin_amdgcn_global_load_lds(                                         \
            (const __attribute__((address_space(1))) void*)src_,                  \
            (__attribute__((address_space(3))) void*)&sh[(baseoff) + (p_*4 + w)*512], \
            16, 0, 0);                                                            \
    }                                                                             \
} while (0)

#define READ_A(d, q) do {                                                         \
    _Pragma("unroll")                                                             \
    for (int ks_ = 0; ks_ < 2; ++ks_) {                                           \
        int rl_ = (q)*16 + lrow;                                                  \
        int cu_ = (ks_*4 + kq) ^ (rl_ & 7);                                       \
        afr[ks_] = *(const short8*)&sh[LDSA(d, wr) + rl_*64 + cu_*8];             \
    }                                                                             \
} while (0)

#define READ_B(d) do {                                                            \
    _Pragma("unroll")                                                             \
    for (int n_ = 0; n_ < 4; ++n_)                                                \
        _Pragma("unroll")                                                         \
        for (int ks_ = 0; ks_ < 2; ++ks_) {                                       \
            int rl_ = n_*16 + lrow;                                               \
            int cu_ = (ks_*4 + kq) ^ (rl_ & 7);                                   \
            bfr[n_][ks_] = *(const short8*)&sh[LDSB(d, wc) + rl_*64 + cu_*8];     \
        }                                                                         \
} while (0)

#define MFMA_Q(q) do {                                                            \
    __builtin_amdgcn_s_setprio(1);                                                \
    _Pragma("unroll")                                                             \
    for (int n_ = 0; n_ < 4; ++n_) {                                              \
        f32x4 t_ = __builtin_amdgcn_mfma_f32_16x16x32_bf16(                       \
            afr[0], bfr[n_][0], acc[q][n_], 0, 0, 0);                             \
        acc[q][n_] = __builtin_amdgcn_mfma_f32_16x16x32_bf16(                     \
            afr[1], bfr[n_][1], t_, 0, 0, 0);                                     \
    }                                                                             \
    __builtin_amdgcn_s_setprio(0);                                                \
} while (0)

#define BAR()    __builtin_amdgcn_s_barrier()
#define VMCNT4() asm volatile("s_waitcnt vmcnt(4)" ::: "memory")
#define VMCNT0() asm volatile("s_waitcnt vmcnt(0)" ::: "memory")
#define SBAR0()  __builtin_amdgcn_sched_barrier(0)
#define LGKM0()  asm volatile("s_waitcnt lgkmcnt(0)" ::: "memory")
#define LGKM8()  asm volatile("s_waitcnt lgkmcnt(8)" ::: "memory")

#define PHASE_MFMA(q) do { BAR(); LGKM0(); SBAR0(); MFMA_Q(q); BAR(); } while (0)

__global__ __launch_bounds__(256, 2) void k_gemm_lse(const ushort_t* __restrict__ Z,
                                                     float* __restrict__ sumexp) {
    __shared__ __align__(16) ushort_t sh[32768];  // 64 KiB -> 2 blocks/CU

    const int tid  = threadIdx.x;
    const int lane = tid & 63;
    const int w    = tid >> 6;      // wave 0..3
    const int wr   = w >> 1;        // 0..1 (M)
    const int wc   = w & 1;         // 0..1 (N)
    const int lrow = lane & 15;
    const int kq   = lane >> 4;
    const int srow = lane >> 3;            // 0..7
    const int scol = (lane & 7) ^ srow;    // pre-swizzled source unit

    // triangular decode over 2080 = 64*65/2 tiles; XCD chunk (2080 = 8*260)
    int t = (int)blockIdx.x;
    t = (t & 7) * 260 + (t >> 3);
    int bi = (int)((sqrtf(8.0f * (float)t + 1.0f) - 1.0f) * 0.5f);
    while ((bi + 1) * (bi + 2) / 2 <= t) ++bi;
    while (bi * (bi + 1) / 2 > t) --bi;
    const int bj = t - bi * (bi + 1) / 2;
    const bool diag = (bi == bj);
    const int r0 = bi * 128, c0 = bj * 128;

    f32x4  acc[4][4] = {};
    short8 afr[2], bfr[4][2];

    // prologue: K-tile0 -> d0 (B0,B1,A0,A1), K-tile1's B -> d1; 12 loads,
    // vmcnt(4) completes the 8 oldest (= all of d0).
    STAGE(LDSB(0,0), c0, 0, 0);
    STAGE(LDSB(0,1), c0, 1, 0);
    STAGE(LDSA(0,0), r0, 0, 0);
    STAGE(LDSA(0,1), r0, 1, 0);
    STAGE(LDSB(1,0), c0, 0, 1);
    STAGE(LDSB(1,1), c0, 1, 1);
    VMCNT4();
    BAR();
    SBAR0();

    #pragma unroll 1
    for (int i = 0; i < 7; ++i) {
        const int t1 = 2*i + 1, t2 = 2*i + 2, t3 = 2*i + 3;
        READ_B(0); READ_A(0,0); STAGE(LDSA(1,0), r0, 0, t1); LGKM8();
        PHASE_MFMA(0);
        READ_A(0,1);            STAGE(LDSA(1,1), r0, 1, t1);
        PHASE_MFMA(1);
        READ_A(0,2);            STAGE(LDSB(0,0), c0, 0, t2);
        PHASE_MFMA(2);
        READ_A(0,3);            STAGE(LDSB(0,1), c0, 1, t2);
        BAR(); LGKM0(); SBAR0(); MFMA_Q(3);
        VMCNT4();   // 8 oldest (d1.B(t1)x4 + d1.A(t1)x4) done
        BAR(); SBAR0();
        READ_B(1); READ_A(1,0); STAGE(LDSA(0,0), r0, 0, t2); LGKM8();
        PHASE_MFMA(0);
        READ_A(1,1);            STAGE(LDSA(0,1), r0, 1, t2);
        PHASE_MFMA(1);
        READ_A(1,2);            STAGE(LDSB(1,0), c0, 0, t3);
        PHASE_MFMA(2);
        READ_A(1,3);            STAGE(LDSB(1,1), c0, 1, t3);
        BAR(); LGKM0(); SBAR0(); MFMA_Q(3);
        VMCNT4();   // 8 oldest (d0.B(t2)x4 + d0.A(t2)x4) done
        BAR(); SBAR0();
    }

    // epilogue iteration: K-tiles 14 (d0) and 15 (d1); only d1.A(15) staged
    READ_B(0); READ_A(0,0); STAGE(LDSA(1,0), r0, 0, 15); LGKM8();
    PHASE_MFMA(0);
    READ_A(0,1);            STAGE(LDSA(1,1), r0, 1, 15);
    PHASE_MFMA(1);
    READ_A(0,2);
    PHASE_MFMA(2);
    READ_A(0,3);
    BAR(); LGKM0(); SBAR0(); MFMA_Q(3); VMCNT0(); BAR(); SBAR0();
    READ_B(1); READ_A(1,0);
    PHASE_MFMA(0);
    READ_A(1,1);
    PHASE_MFMA(1);
    READ_A(1,2);
    PHASE_MFMA(2);
    READ_A(1,3);
    LGKM0(); SBAR0(); MFMA_Q(3);

    // fused epilogue (round-2-verified geometry): e = exp(10c - 10);
    // row sums always; col sums (transpose contribution) if off-diagonal.
    float rp[4][4] = {};
    float cp[4]    = {};
    #pragma unroll
    for (int m = 0; m < 4; ++m)
        #pragma unroll
        for (int n = 0; n < 4; ++n)
            #pragma unroll
            for (int r = 0; r < 4; ++r) {
                float e = __expf(acc[m][n][r] * 10.0f - 10.0f);
                rp[m][r] += e;
                cp[n]    += e;
            }

    #pragma unroll
    for (int m = 0; m < 4; ++m) {
        #pragma unroll
        for (int off = 1; off < 16; off <<= 1)
            #pragma unroll
            for (int r = 0; r < 4; ++r) rp[m][r] += __shfl_xor(rp[m][r], off);
        if (lrow == 0) {
            int rowbase = r0 + wr * 64 + m * 16 + kq * 4;
            #pragma unroll
            for (int r = 0; r < 4; ++r) atomicAdd(&sumexp[rowbase + r], rp[m][r]);
        }
    }

    if (!diag) {
        #pragma unroll
        for (int n = 0; n < 4; ++n) {
            cp[n] += __shfl_xor(cp[n], 16);
            cp[n] += __shfl_xor(cp[n], 32);
        }
        if (kq == 0) {
            #pragma unroll
            for (int n = 0; n < 4; ++n)
                atomicAdd(&sumexp[c0 + wc * 64 + n * 16 + lrow], cp[n]);
        }
    }
}

// ---------------------------------------------------------------- kernel 3
__global__ __launch_bounds__(1024) void k_finalize(const float* __restrict__ sumexp,
                                                   const float* __restrict__ dotz,
                                                   float* __restrict__ out) {
    double s = 0.0;
    for (int r = threadIdx.x; r < N_ROWS; r += 1024)
        s += (double)(10.0f + logf(sumexp[r]) - 10.0f * dotz[r]);

    const int lane = threadIdx.x & 63;
    const int wid  = threadIdx.x >> 6;
    #pragma unroll
    for (int off = 32; off; off >>= 1) s += __shfl_down(s, off);

    __shared__ double sh[16];
    if (lane == 0) sh[wid] = s;
    __syncthreads();
    if (threadIdx.x == 0) {
        double tot = 0.0;
        #pragma unroll
        for (int i = 0; i < 16; ++i) tot += sh[i];
        out[0] = (float)(tot / (double)N_ROWS);
    }
}

// ----------------------------------------------------------------
extern "C" void kernel_launch(void* const* d_in, const int* in_sizes, int n_in,
                              void* d_out, int out_size, void* d_ws, size_t ws_size,
                              hipStream_t stream) {
    const float* X = (const float*)d_in[0];
    float* out = (float*)d_out;

    // ws: Z bf16 [8192*1024] (16MB) | sumexp f32[8192] | dotz f32[8192]
    ushort_t* Z      = (ushort_t*)d_ws;
    float*    sumexp = (float*)((char*)d_ws + (size_t)N_ROWS * N_DIM * 2);
    float*    dotz   = sumexp + N_ROWS;

    k_normalize<<<N_ROWS / 4, 256, 0, stream>>>(X, Z, sumexp, dotz);

    const int nblk = 64 * 65 / 2;  // 2080 triangular 128^2 tiles
    k_gemm_lse<<<nblk, 256, 0, stream>>>(Z, sumexp);

    k_finalize<<<1, 1024, 0, stream>>>(sumexp, dotz, out);
}